// Round 7
// baseline (3268.927 us; speedup 1.0000x reference)
//
#include <hip/hip_runtime.h>

// ---------------------------------------------------------------------------
// Fused decoder: B=8192 x 40 steps, one WG of 512 threads (8 waves) per 32
// rows, grid=256 (1 WG/CU, 2 waves/SIMD, VGPR budget 256). 16x16x32 bf16 MFMA.
// R7: inline-asm global_load_dwordx4 weight loads (RA is FORCED to keep
// distinct in-flight dest regs -> real MLP), counted s_waitcnt vmcnt(N),
// sched_barrier fences, lgkmcnt-only barriers. Gates GEMM: depth-2 register
// double-buffer of 8-load chunks; next-step chunks + F-weights + eps issued
// in phase E and kept in flight across barriers.
// ---------------------------------------------------------------------------

#define BDIM  8192
#define HDIM  256
#define FDIM  128
#define ZDIM  64
#define TDIM  43
#define STEPS 40

typedef __attribute__((ext_vector_type(8))) __bf16 bf16x8;
typedef __attribute__((ext_vector_type(4))) float  f32x4;
typedef __attribute__((ext_vector_type(4))) int    i32x4;

// LDS activation buffer (cols are bf16 elements)
#define ACT_STRIDE 3248   // bytes/row; 812 dw == 12 (mod 32), +16B stagger per 8 rows
#define C_Z   0           // z          (64)
#define C_Y0  64          // y parity 0 (128)
#define C_Y1  192         // y parity 1 (128)
#define C_H0  320         // h parity 0 (256)
#define C_H1  576         // h parity 1 (256)
#define C_C   832         // c_new      (256)   (holds h_i during startup folds)
#define C_T0  1088        // y1         (128)
#define C_T1  1216        // y2         (128)
#define C_HZ  1344        // hz  (inf)  (64)
#define C_HZP 1408        // hzp (prior)(64)
#define C_B4  1472        // h_i@w4+b4 fold, bf16 (64)
#define C_B7  1536        // h_i@w7+b7 fold, bf16 (64)

// packed-weight offsets in __bf16 elements
#define PW_GS  0u         // gates [z|yp|h] K=448 N=1024 (KT=14)
#define PW_GHI 458752u    // gates h_i part K=256 N=1024 (KT=8)
#define PW_W1  720896u    // K=256 N=128 (KT=8)
#define PW_W2  753664u    // K=128 N=128 (KT=4)
#define PW_W3  770048u    // K=128 N=128 (KT=4)
#define PW_W4S 786432u    // w4 rows 256:768 [c|y|yp] K=512 N=64 (KT=16)
#define PW_W4H 819200u    // w4 rows 0:256 K=256 N=64 (KT=8)
#define PW_W5  835584u    // K=64 N=64 (KT=2)
#define PW_W6  839680u
#define PW_W7S 843776u    // w7 rows 256:640 [c|yp] K=384 N=64 (KT=12)
#define PW_W7H 868352u    // w7 rows 0:256 K=256 N=64 (KT=8)
#define PW_W8  884736u
#define PW_W9  888832u

#define SB() __builtin_amdgcn_sched_barrier(0)
#define VMW(N)                                             \
  do {                                                     \
    asm volatile("s_waitcnt vmcnt(" #N ")" ::: "memory");  \
    SB();                                                  \
  } while (0)

__device__ __forceinline__ int act_off(int row, int col) {
  return row * ACT_STRIDE + ((row >> 3) << 4) + (col << 1);
}
__device__ __forceinline__ f32x4 mfma16(bf16x8 a, bf16x8 b, f32x4 c) {
  return __builtin_amdgcn_mfma_f32_16x16x32_bf16(a, b, c, 0, 0, 0);
}
__device__ __forceinline__ float sigm(float x) { return 1.f / (1.f + __expf(-x)); }
__device__ __forceinline__ float tanh_f(float x) {
  float t = __expf(-2.f * fabsf(x));
  float r = (1.f - t) / (1.f + t);
  return x < 0.f ? -r : r;
}
__device__ __forceinline__ void wg_barrier() {
  asm volatile("s_waitcnt lgkmcnt(0)" ::: "memory");
  __builtin_amdgcn_s_barrier();
  __builtin_amdgcn_sched_barrier(0);
}
// forced-MLP loads: asm volatile cannot be sunk/serialized by the compiler
__device__ __forceinline__ bf16x8 gld(const bf16x8* p) {
  i32x4 r;
  asm volatile("global_load_dwordx4 %0, %1, off" : "=v"(r) : "v"(p));
  return __builtin_bit_cast(bf16x8, r);
}
__device__ __forceinline__ float gldf(const float* p) {
  float r;
  asm volatile("global_load_dword %0, %1, off" : "=v"(r) : "v"(p));
  return r;
}
// A-fragment read: lane l holds A[mt*16 + (l&15)][k = (l>>4)*8 + j]
__device__ __forceinline__ bf16x8 aread(const unsigned char* actb, int mt, int col,
                                        int lane) {
  return *(const bf16x8*)(actb + act_off(mt * 16 + (lane & 15), col + ((lane >> 4) << 3)));
}
__device__ __forceinline__ void st16(unsigned char* actb, int col, int mt, int rsub,
                                     f32x4 v, float bv) {
#pragma unroll
  for (int r = 0; r < 4; ++r)
    *(__bf16*)(actb + act_off(mt * 16 + rsub + r, col)) = (__bf16)fmaxf(v[r] + bv, 0.f);
}
__device__ __forceinline__ unsigned int pk2(float a, float b) {
  union { __bf16 h; unsigned short u; } x, y;
  x.h = (__bf16)a; y.h = (__bf16)b;
  return (unsigned int)x.u | ((unsigned int)y.u << 16);
}
__device__ __forceinline__ float upkf(unsigned int u, int hi) {
  union { unsigned int i; float f; } c;
  c.i = hi ? (u & 0xffff0000u) : (u << 16);
  return c.f;
}

// ---------------------------------------------------------------------------
// Pack (up to 3 K-stacked row segments) into 16-wide B-fragments:
// frag f=(nt*KT+kt)*64+lane holds W[kt*32+(lane>>4)*8+j][nt*16+(lane&15)].
// ---------------------------------------------------------------------------
struct PSeg { const float* p; int row0; int len; };

__global__ __launch_bounds__(256) void pack_w(PSeg s0, PSeg s1, PSeg s2,
                                              int K, int N, __bf16* __restrict__ dst) {
  int f = blockIdx.x * 256 + threadIdx.x;
  int KT = K >> 5;
  int total = KT * (N >> 4) * 64;
  if (f >= total) return;
  int lane = f & 63;
  int tile = f >> 6;
  int kt = tile % KT;
  int nt = tile / KT;
  int k0 = kt * 32 + ((lane >> 4) << 3);
  int n = (nt << 4) + (lane & 15);
  bf16x8 v;
#pragma unroll
  for (int j = 0; j < 8; ++j) {
    int k = k0 + j;
    const float* src;
    int r;
    if (k < s0.len) { src = s0.p; r = s0.row0 + k; }
    else if (k < s0.len + s1.len) { src = s1.p; r = s1.row0 + (k - s0.len); }
    else { src = s2.p; r = s2.row0 + (k - s0.len - s1.len); }
    v[j] = (__bf16)src[(size_t)r * N + n];
  }
  *(bf16x8*)(dst + (size_t)f * 8) = v;
}

struct Params {
  const float *h_i, *input_t, *eps_inf, *eps_prior;
  const float *b_lstm, *b1, *b2, *b3, *b4, *b5, *b6, *b7, *b8, *b9;
  const float *alpha, *beta, *mu0;
  const __bf16* wpack;
  float* out;
};

// issue one gates kt-chunk: 8 frags (4 gates x 2 ntiles) for wave w
__device__ __forceinline__ void issue_gchunk(bf16x8 (&wf)[8], const bf16x8* wgs,
                                             int w, int lane, int kt) {
#pragma unroll
  for (int g = 0; g < 4; ++g)
#pragma unroll
    for (int t = 0; t < 2; ++t)
      wf[g * 2 + t] =
          gld(wgs + ((size_t)((g * 16 + w * 2 + t) * 14 + kt) << 6) + lane);
}

__global__ __launch_bounds__(512) __attribute__((amdgpu_waves_per_eu(2, 2)))
void decoder_main(Params p) {
  __shared__ __align__(16) unsigned char act[32 * ACT_STRIDE];  // 103936 B
  __shared__ float fbuf[2048];                                  // 8192 B
  __shared__ float inten[STEPS * 32];                           // 5120 B

  const int tid = threadIdx.x;
  const int w = tid >> 6;
  const int lane = tid & 63;
  const int ln16 = lane & 15;
  const int rsub = (lane >> 4) << 2;
  const int r0 = blockIdx.x * 32;

  for (int i = tid; i < (32 * ACT_STRIDE) / 4; i += 512) ((unsigned int*)act)[i] = 0u;
  __syncthreads();
  for (int i = tid; i < 32 * 256; i += 512) {
    int row = i >> 8, col = i & 255;
    *(__bf16*)(act + act_off(row, C_C + col)) =
        (__bf16)p.h_i[(size_t)(r0 + row) * HDIM + col];
  }
  {
    float ab = p.alpha[0] * p.beta[0], mu = p.mu0[0];
    for (int t = tid; t < 32 * STEPS; t += 512) {
      int row = t & 31, j = t >> 5;
      const float* tp = p.input_t + (size_t)(r0 + row) * TDIM;
      float tc = tp[j + 3];
      float s = 0.f;
      for (int idx = 0; idx < j + 3; ++idx) s += __expf(tp[idx] - tc);
      inten[j * 32 + row] = mu + ab * s;
    }
  }
  __syncthreads();

  const __bf16* W = p.wpack;
  const bf16x8* wgs = (const bf16x8*)(W + PW_GS);
  const bf16x8* wghi = (const bf16x8*)(W + PW_GHI);
  const bf16x8* w1p = (const bf16x8*)(W + PW_W1);
  const bf16x8* w2p = (const bf16x8*)(W + PW_W2);
  const bf16x8* w3p = (const bf16x8*)(W + PW_W3);
  const bf16x8* w4s = (const bf16x8*)(W + PW_W4S);
  const bf16x8* w4h = (const bf16x8*)(W + PW_W4H);
  const bf16x8* w5p = (const bf16x8*)(W + PW_W5);
  const bf16x8* w6p = (const bf16x8*)(W + PW_W6);
  const bf16x8* w7s = (const bf16x8*)(W + PW_W7S);
  const bf16x8* w7h = (const bf16x8*)(W + PW_W7H);
  const bf16x8* w8p = (const bf16x8*)(W + PW_W8);
  const bf16x8* w9p = (const bf16x8*)(W + PW_W9);

  // ---- startup folds (plain C loads; latency uncritical) ----
  uint2 gbp[4][2][2];  // h_i@Wx_hi + b_lstm, packed bf16 per (gate, ntile, mtile)
  {
    f32x4 g4[4][2][2] = {};
#pragma unroll
    for (int kt = 0; kt < 8; ++kt) {
      bf16x8 a0 = aread(act, 0, C_C + kt * 32, lane);
      bf16x8 a1 = aread(act, 1, C_C + kt * 32, lane);
#pragma unroll
      for (int g = 0; g < 4; ++g)
#pragma unroll
        for (int t = 0; t < 2; ++t) {
          bf16x8 b = wghi[((size_t)((g * 16 + w * 2 + t) * 8 + kt)) * 64 + lane];
          g4[g][t][0] = mfma16(a0, b, g4[g][t][0]);
          g4[g][t][1] = mfma16(a1, b, g4[g][t][1]);
        }
    }
#pragma unroll
    for (int g = 0; g < 4; ++g)
#pragma unroll
      for (int t = 0; t < 2; ++t) {
        float bv = p.b_lstm[g * 256 + (w * 2 + t) * 16 + ln16];
#pragma unroll
        for (int mt = 0; mt < 2; ++mt) {
          gbp[g][t][mt].x = pk2(g4[g][t][mt][0] + bv, g4[g][t][mt][1] + bv);
          gbp[g][t][mt].y = pk2(g4[g][t][mt][2] + bv, g4[g][t][mt][3] + bv);
        }
      }
  }
  {  // h_i@w4h+b4 -> C_B4 and h_i@w7h+b7 -> C_B7 (each wave: n=w&3, mt=w>>2)
    int n = w & 3, mt = w >> 2;
    f32x4 v4 = {}, v7 = {};
#pragma unroll
    for (int kt = 0; kt < 8; ++kt) {
      bf16x8 a = aread(act, mt, C_C + kt * 32, lane);
      v4 = mfma16(a, w4h[(size_t)(n * 8 + kt) * 64 + lane], v4);
      v7 = mfma16(a, w7h[(size_t)(n * 8 + kt) * 64 + lane], v7);
    }
    float b4v = p.b4[n * 16 + ln16], b7v = p.b7[n * 16 + ln16];
#pragma unroll
    for (int r = 0; r < 4; ++r) {
      int row = mt * 16 + rsub + r;
      *(__bf16*)(act + act_off(row, C_B4 + n * 16 + ln16)) = (__bf16)(v4[r] + b4v);
      *(__bf16*)(act + act_off(row, C_B7 + n * 16 + ln16)) = (__bf16)(v7[r] + b7v);
    }
  }
  f32x4 c_st[2][2] = {};
  // step-invariant bias hoists
  const int nw = w & 3, mw = w >> 2;
  float bv1 = p.b1[w * 16 + ln16], bv2 = p.b2[w * 16 + ln16], bv3 = p.b3[w * 16 + ln16];
  float b5v = p.b5[nw * 16 + ln16], b6v = p.b6[nw * 16 + ln16];
  float b8v = p.b8[nw * 16 + ln16], b9v = p.b9[nw * 16 + ln16];
  __syncthreads();

  float* outy = p.out;
  float* outm = p.out + (size_t)BDIM * STEPS * FDIM;
  float* outl = outm + (size_t)BDIM * STEPS * ZDIM;
  float* outz = outl + (size_t)BDIM * STEPS * ZDIM;
  float* outzp = outz + (size_t)BDIM * STEPS * ZDIM;

  // gates weight double-buffer (persists across barriers in registers)
  bf16x8 wgbuf[2][8];
  issue_gchunk(wgbuf[0], wgs, w, lane, 0);
  issue_gchunk(wgbuf[1], wgs, w, lane, 1);
  // phase-F weights + eps_inf for step 0 (issued after gates -> drained first? no:
  // they are NEWER; F uses VMW(16) which needs them older. So issue BEFORE gates
  // next time (phase E); for step 0 we instead load them in phase E of step -1
  // equivalent: issue here AFTER is wrong -> keep F-weights per-step from E, and
  // for step 0 phase E has not run. Solution: phases C..F of step 0 behave like
  // any step because E of step 0 issues them for F of step 0. F of step 0 only
  // needs w5/w6/eps issued in E of step 0. OK: nothing more to do here.

  for (int j = 0; j < STEPS; ++j) {
    const int yW = (j & 1) ? C_Y1 : C_Y0, yR = (j & 1) ? C_Y0 : C_Y1;
    const int hW = (j & 1) ? C_H1 : C_H0, hR = (j & 1) ? C_H0 : C_H1;

    // ---- A: gates = [z|yp|h]@Wgs (+h_i fold in acc init) ----
    {
      f32x4 acc[4][2][2];
#pragma unroll
      for (int g = 0; g < 4; ++g)
#pragma unroll
        for (int t = 0; t < 2; ++t)
#pragma unroll
          for (int mt = 0; mt < 2; ++mt) {
            acc[g][t][mt][0] = upkf(gbp[g][t][mt].x, 0);
            acc[g][t][mt][1] = upkf(gbp[g][t][mt].x, 1);
            acc[g][t][mt][2] = upkf(gbp[g][t][mt].y, 0);
            acc[g][t][mt][3] = upkf(gbp[g][t][mt].y, 1);
          }
#pragma unroll
      for (int kt = 0; kt < 14; ++kt) {
        if (kt < 13) { VMW(8); } else { VMW(0); }  // chunk kt complete
        int col = (kt < 2) ? (C_Z + kt * 32)
                           : (kt < 6) ? (yR + (kt - 2) * 32) : (hR + (kt - 6) * 32);
        bf16x8 a0 = aread(act, 0, col, lane);
        bf16x8 a1 = aread(act, 1, col, lane);
#pragma unroll
        for (int g = 0; g < 4; ++g)
#pragma unroll
          for (int t = 0; t < 2; ++t) {
            acc[g][t][0] = mfma16(a0, wgbuf[kt & 1][g * 2 + t], acc[g][t][0]);
            acc[g][t][1] = mfma16(a1, wgbuf[kt & 1][g * 2 + t], acc[g][t][1]);
          }
        SB();  // keep the refill below the MFMAs in final order
        if (kt + 2 < 14) issue_gchunk(wgbuf[kt & 1], wgs, w, lane, kt + 2);
      }
#pragma unroll
      for (int t = 0; t < 2; ++t) {
        int colc = (w * 2 + t) * 16 + ln16;
#pragma unroll
        for (int mt = 0; mt < 2; ++mt)
#pragma unroll
          for (int r = 0; r < 4; ++r) {
            int row = mt * 16 + rsub + r;
            float ig = sigm(acc[0][t][mt][r]);
            float fg = sigm(acc[1][t][mt][r]);
            float gg = tanh_f(acc[2][t][mt][r]);
            float og = sigm(acc[3][t][mt][r]);
            float cn = fg * c_st[t][mt][r] + ig * gg;
            float hn = og * tanh_f(cn);
            c_st[t][mt][r] = inten[j * 32 + row] * cn;
            *(__bf16*)(act + act_off(row, C_C + colc)) = (__bf16)cn;
            *(__bf16*)(act + act_off(row, hW + colc)) = (__bf16)hn;
          }
      }
    }
    wg_barrier();

    // ---- B: y1 = relu(h@w1+b1)  AND  prior full-K -> hzp ----
    {
      bf16x8 wy[8];
#pragma unroll
      for (int kt = 0; kt < 8; ++kt)
        wy[kt] = gld(w1p + (size_t)(w * 8 + kt) * 64 + lane);
      bf16x8 wpr[12];
#pragma unroll
      for (int kt = 0; kt < 12; ++kt)
        wpr[kt] = gld(w7s + (size_t)(nw * 12 + kt) * 64 + lane);
      VMW(12);  // wy complete
      f32x4 a0 = {}, a1 = {};
#pragma unroll
      for (int kt = 0; kt < 8; ++kt) {
        a0 = mfma16(aread(act, 0, hW + kt * 32, lane), wy[kt], a0);
        a1 = mfma16(aread(act, 1, hW + kt * 32, lane), wy[kt], a1);
      }
      st16(act, C_T0 + w * 16 + ln16, 0, rsub, a0, bv1);
      st16(act, C_T0 + w * 16 + ln16, 1, rsub, a1, bv1);
      VMW(0);  // wpr complete
      f32x4 v = {};
#pragma unroll
      for (int kt = 0; kt < 12; ++kt) {
        int col = (kt < 8) ? (C_C + kt * 32) : (yR + (kt - 8) * 32);
        v = mfma16(aread(act, mw, col, lane), wpr[kt], v);
      }
#pragma unroll
      for (int r = 0; r < 4; ++r) {
        int row = mw * 16 + rsub + r;
        float s = v[r] + (float)*(const __bf16*)(act + act_off(row, C_B7 + nw * 16 + ln16));
        *(__bf16*)(act + act_off(row, C_HZP + nw * 16 + ln16)) = (__bf16)fmaxf(s, 0.f);
      }
    }
    wg_barrier();

    // ---- C: y2  AND  mean_p/lv_p + sample zp ----
    {
      bf16x8 w2f[4];
#pragma unroll
      for (int kt = 0; kt < 4; ++kt)
        w2f[kt] = gld(w2p + (size_t)(w * 4 + kt) * 64 + lane);
      bf16x8 w8f[2], w9f[2];
#pragma unroll
      for (int kt = 0; kt < 2; ++kt) {
        w8f[kt] = gld(w8p + (size_t)(nw * 2 + kt) * 64 + lane);
        w9f[kt] = gld(w9p + (size_t)(nw * 2 + kt) * 64 + lane);
      }
      float ep[4];
#pragma unroll
      for (int r = 0; r < 4; ++r)
        ep[r] = gldf(p.eps_prior + ((size_t)j * BDIM + r0 + mw * 16 + rsub + r) * ZDIM +
                     nw * 16 + ln16);
      VMW(8);  // w2f complete
      f32x4 a0 = {}, a1 = {};
#pragma unroll
      for (int kt = 0; kt < 4; ++kt) {
        a0 = mfma16(aread(act, 0, C_T0 + kt * 32, lane), w2f[kt], a0);
        a1 = mfma16(aread(act, 1, C_T0 + kt * 32, lane), w2f[kt], a1);
      }
      st16(act, C_T1 + w * 16 + ln16, 0, rsub, a0, bv2);
      st16(act, C_T1 + w * 16 + ln16, 1, rsub, a1, bv2);
      VMW(0);  // w8f/w9f/ep complete
      f32x4 vm = {}, vl = {};
#pragma unroll
      for (int kt = 0; kt < 2; ++kt) {
        bf16x8 a = aread(act, mw, C_HZP + kt * 32, lane);
        vm = mfma16(a, w8f[kt], vm);
        vl = mfma16(a, w9f[kt], vl);
      }
#pragma unroll
      for (int r = 0; r < 4; ++r) {
        int row = mw * 16 + rsub + r, col = nw * 16 + ln16;
        float mp = fmaxf(vm[r] + b8v, 0.f), lp = fmaxf(vl[r] + b9v, 0.f);
        float zp = mp + ep[r] * __expf(0.5f * lp);
        __builtin_nontemporal_store(
            zp, outzp + ((size_t)(r0 + row) * STEPS + j) * ZDIM + col);
      }
    }
    wg_barrier();

    // ---- D: y3 -> yW + outy  AND  hz partial over [c|yp] -> fbuf ----
    {
      bf16x8 w3f[4];
#pragma unroll
      for (int kt = 0; kt < 4; ++kt)
        w3f[kt] = gld(w3p + (size_t)(w * 4 + kt) * 64 + lane);
      bf16x8 w4c[12];
#pragma unroll
      for (int kk = 0; kk < 12; ++kk) {
        int kt = (kk < 8) ? kk : (kk + 4);  // c-part kt 0..7, yp-part kt 12..15
        w4c[kk] = gld(w4s + (size_t)(nw * 16 + kt) * 64 + lane);
      }
      VMW(12);  // w3f complete
      f32x4 a0 = {}, a1 = {};
#pragma unroll
      for (int kt = 0; kt < 4; ++kt) {
        a0 = mfma16(aread(act, 0, C_T1 + kt * 32, lane), w3f[kt], a0);
        a1 = mfma16(aread(act, 1, C_T1 + kt * 32, lane), w3f[kt], a1);
      }
#pragma unroll
      for (int mt = 0; mt < 2; ++mt) {
        f32x4 vv = mt ? a1 : a0;
#pragma unroll
        for (int r = 0; r < 4; ++r) {
          int row = mt * 16 + rsub + r;
          float yv = fmaxf(vv[r] + bv3, 0.f);
          *(__bf16*)(act + act_off(row, yW + w * 16 + ln16)) = (__bf16)yv;
          __builtin_nontemporal_store(
              yv, outy + ((size_t)(r0 + row) * STEPS + j) * FDIM + w * 16 + ln16);
        }
      }
      VMW(0);  // w4c complete
      f32x4 v = {};
#pragma unroll
      for (int kk = 0; kk < 12; ++kk) {
        int col = (kk < 8) ? (C_C + kk * 32) : (yR + (kk - 8) * 32);
        v = mfma16(aread(act, mw, col, lane), w4c[kk], v);
      }
#pragma unroll
      for (int r = 0; r < 4; ++r)
        fbuf[(mw * 16 + rsub + r) * 64 + nw * 16 + ln16] = v[r];
    }
    wg_barrier();

    // ---- E: issue {hz-y wf, w5/w6, eps_inf, next-step gates c0/c1};
    //      then hz y-part + combine + fold -> C_HZ ----
    bf16x8 w5f[2], w6f[2];
    float ei[4];
    {
      bf16x8 w4y[4];
#pragma unroll
      for (int kt = 8; kt < 12; ++kt)
        w4y[kt - 8] = gld(w4s + (size_t)(nw * 16 + kt) * 64 + lane);
#pragma unroll
      for (int kt = 0; kt < 2; ++kt) {
        w5f[kt] = gld(w5p + (size_t)(nw * 2 + kt) * 64 + lane);
        w6f[kt] = gld(w6p + (size_t)(nw * 2 + kt) * 64 + lane);
      }
#pragma unroll
      for (int r = 0; r < 4; ++r)
        ei[r] = gldf(p.eps_inf + ((size_t)j * BDIM + r0 + mw * 16 + rsub + r) * ZDIM +
                     nw * 16 + ln16);
      issue_gchunk(wgbuf[0], wgs, w, lane, 0);  // next step (harmless on last)
      issue_gchunk(wgbuf[1], wgs, w, lane, 1);
      VMW(24);  // w4y complete; w5/w6/eps + gates (24) stay in flight
      f32x4 v = {};
#pragma unroll
      for (int kt = 8; kt < 12; ++kt)
        v = mfma16(aread(act, mw, yW + (kt - 8) * 32, lane), w4y[kt - 8], v);
#pragma unroll
      for (int r = 0; r < 4; ++r) {
        int row = mw * 16 + rsub + r, cc = nw * 16 + ln16;
        float s = v[r] + fbuf[row * 64 + cc] +
                  (float)*(const __bf16*)(act + act_off(row, C_B4 + cc));
        *(__bf16*)(act + act_off(row, C_HZ + cc)) = (__bf16)fmaxf(s, 0.f);
      }
    }
    wg_barrier();

    // ---- F: mean_j/lv_j + sample z -> outputs + C_Z ----
    {
      VMW(16);  // w5f/w6f/ei complete; gates c0/c1 (16) remain in flight
      f32x4 vm = {}, vl = {};
#pragma unroll
      for (int kt = 0; kt < 2; ++kt) {
        bf16x8 a = aread(act, mw, C_HZ + kt * 32, lane);
        vm = mfma16(a, w5f[kt], vm);
        vl = mfma16(a, w6f[kt], vl);
      }
#pragma unroll
      for (int r = 0; r < 4; ++r) {
        int row = mw * 16 + rsub + r, col = nw * 16 + ln16;
        float m = fmaxf(vm[r] + b5v, 0.f), l = fmaxf(vl[r] + b6v, 0.f);
        float zn = m + ei[r] * __expf(0.5f * l);
        size_t ob = ((size_t)(r0 + row) * STEPS + j) * ZDIM + col;
        __builtin_nontemporal_store(m, outm + ob);
        __builtin_nontemporal_store(l, outl + ob);
        __builtin_nontemporal_store(zn, outz + ob);
        *(__bf16*)(act + act_off(row, C_Z + col)) = (__bf16)zn;
      }
    }
    wg_barrier();
  }
}

extern "C" void kernel_launch(void* const* d_in, const int* in_sizes, int n_in,
                              void* d_out, int out_size, void* d_ws, size_t ws_size,
                              hipStream_t stream) {
  const float* h_i = (const float*)d_in[0];
  const float* input_t = (const float*)d_in[1];
  const float* eps_inf = (const float*)d_in[2];
  const float* eps_prior = (const float*)d_in[3];
  const float* Wx = (const float*)d_in[4];
  const float* Wh = (const float*)d_in[5];
  const float* b_lstm = (const float*)d_in[6];
  const float* w1 = (const float*)d_in[7];  const float* b1 = (const float*)d_in[8];
  const float* w2 = (const float*)d_in[9];  const float* b2 = (const float*)d_in[10];
  const float* w3 = (const float*)d_in[11]; const float* b3 = (const float*)d_in[12];
  const float* w4 = (const float*)d_in[13]; const float* b4 = (const float*)d_in[14];
  const float* w5 = (const float*)d_in[15]; const float* b5 = (const float*)d_in[16];
  const float* w6 = (const float*)d_in[17]; const float* b6 = (const float*)d_in[18];
  const float* w7 = (const float*)d_in[19]; const float* b7 = (const float*)d_in[20];
  const float* w8 = (const float*)d_in[21]; const float* b8 = (const float*)d_in[22];
  const float* w9 = (const float*)d_in[23]; const float* b9 = (const float*)d_in[24];
  const float* alpha = (const float*)d_in[25];
  const float* beta = (const float*)d_in[26];
  const float* mu0 = (const float*)d_in[27];
  __bf16* ws = (__bf16*)d_ws;

  auto S = [](const float* ptr, int row0, int len) {
    PSeg s; s.p = ptr; s.row0 = row0; s.len = len; return s;
  };
  PSeg Zs; Zs.p = nullptr; Zs.row0 = 0; Zs.len = 0;
  auto L = [&](PSeg a, PSeg b, PSeg c, int K, int N, unsigned off) {
    int total = (K / 32) * (N / 16) * 64;
    pack_w<<<(total + 255) / 256, 256, 0, stream>>>(a, b, c, K, N, ws + off);
  };
  L(S(Wx, 0, 64), S(Wx, 320, 128), S(Wh, 0, 256), 448, 1024, PW_GS);  // [z|yp|h]
  L(S(Wx, 64, 256), Zs, Zs, 256, 1024, PW_GHI);
  L(S(w1, 0, 256), Zs, Zs, 256, 128, PW_W1);
  L(S(w2, 0, 128), Zs, Zs, 128, 128, PW_W2);
  L(S(w3, 0, 128), Zs, Zs, 128, 128, PW_W3);
  L(S(w4, 256, 512), Zs, Zs, 512, 64, PW_W4S);  // [c|y|yp]
  L(S(w4, 0, 256), Zs, Zs, 256, 64, PW_W4H);
  L(S(w5, 0, 64), Zs, Zs, 64, 64, PW_W5);
  L(S(w6, 0, 64), Zs, Zs, 64, 64, PW_W6);
  L(S(w7, 256, 384), Zs, Zs, 384, 64, PW_W7S);  // [c|yp]
  L(S(w7, 0, 256), Zs, Zs, 256, 64, PW_W7H);
  L(S(w8, 0, 64), Zs, Zs, 64, 64, PW_W8);
  L(S(w9, 0, 64), Zs, Zs, 64, 64, PW_W9);

  Params p;
  p.h_i = h_i; p.input_t = input_t; p.eps_inf = eps_inf; p.eps_prior = eps_prior;
  p.b_lstm = b_lstm; p.b1 = b1; p.b2 = b2; p.b3 = b3; p.b4 = b4; p.b5 = b5;
  p.b6 = b6; p.b7 = b7; p.b8 = b8; p.b9 = b9;
  p.alpha = alpha; p.beta = beta; p.mu0 = mu0;
  p.wpack = ws;
  p.out = (float*)d_out;

  decoder_main<<<256, 512, 0, stream>>>(p);
}